// Round 15
// baseline (1136.177 us; speedup 1.0000x reference)
//
#include <hip/hip_runtime.h>
#include <hip/hip_bf16.h>
#include <cstddef>
#include <cstdint>

// Problem constants
constexpr int NB    = 16;
constexpr int NN    = 2000;
constexpr int TH    = 24;
constexpr int TF    = 24;
constexpr int HID   = 64;
constexpr int NF    = 8;
constexpr int NODES = NB * NN;      // 32000
constexpr int ETOT  = NODES * 32;   // 1,024,000
constexpr int EPB   = NN * 32;      // 64,000 edges per batch
constexpr int TT    = TH + TF;      // 48
constexpr int NSL   = 16;           // dst slices per batch
constexpr int SLN   = NN / NSL;     // 125 nodes per slice
constexpr int EBLK  = 32;           // nodes per encoder block
constexpr int NEBLK = NODES / EBLK; // 1000
constexpr int DBLK  = 64;           // nodes per decoder block
constexpr int NDBLK = NODES / DBLK; // 500

typedef __attribute__((ext_vector_type(8))) short bf16x8;
typedef __attribute__((ext_vector_type(4))) float f32x4;
typedef uint16_t u16;

__device__ __forceinline__ float sigmoidf_(float x) { return 1.f / (1.f + __expf(-x)); }
__device__ __forceinline__ float tanhf_(float x) {
    float e = __expf(2.f * x);
    return 1.f - 2.f / (e + 1.f);
}
__device__ __forceinline__ u16 bfh(float x) {
    __hip_bfloat16 b = __float2bfloat16(x);
    u16 u; __builtin_memcpy(&u, &b, 2); return u;
}
__device__ __forceinline__ float bff(u16 u) { return __uint_as_float(((uint32_t)u) << 16); }
__device__ __forceinline__ uint32_t pk(u16 a, u16 b) { return (uint32_t)a | ((uint32_t)b << 16); }

// ---------------- setup kernels ----------------
// sliced per-(batch,dst-range) LDS histogram degree: 256 blocks, full occupancy
__global__ __launch_bounds__(256) void k_deg3(const int* __restrict__ ei,
                                              float* __restrict__ deg)
{
    __shared__ int h[SLN];
    const int b = blockIdx.x >> 4, s = blockIdx.x & 15;
    const int lo = s * SLN;                     // within-batch range [lo, lo+SLN)
    for (int i = threadIdx.x; i < SLN; i += 256) h[i] = 0;
    __syncthreads();
    const int base = b * EPB;
    for (int i = threadIdx.x; i < EPB; i += 256) {
        int d = ei[ETOT + base + i] - b * NN;
        if (d >= lo && d < lo + SLN) atomicAdd(&h[d - lo], 1);
    }
    __syncthreads();
    for (int i = threadIdx.x; i < SLN; i += 256) deg[b * NN + lo + i] = (float)h[i];
}

__global__ __launch_bounds__(256) void k_scan(const float* __restrict__ degf,
                                              int* __restrict__ row0)
{
    __shared__ int part[256];
    const int tid = threadIdx.x;
    const int per = NODES / 256;
    const int base = tid * per;
    int s = 0;
    for (int i = 0; i < per; i++) s += (int)degf[base + i];
    part[tid] = s;
    __syncthreads();
    for (int off = 1; off < 256; off <<= 1) {
        int v = (tid >= off) ? part[tid - off] : 0;
        __syncthreads();
        part[tid] += v;
        __syncthreads();
    }
    int run = (tid == 0) ? 0 : part[tid - 1];
    for (int i = 0; i < per; i++) {
        row0[base + i] = run;
        run += (int)degf[base + i];
    }
    if (tid == 255) row0[NODES] = run;
}

__global__ void k_dis(float* __restrict__ dis) {
    int i = blockIdx.x * blockDim.x + threadIdx.x;
    if (i < NODES) {
        float d = dis[i];
        dis[i] = (d > 0.f) ? rsqrtf(fmaxf(d, 1.f)) : 0.f;
    }
}

// sliced CSR fill: 256 blocks, LDS counters per 125-node slice
__global__ __launch_bounds__(256) void k_fill3(const int* __restrict__ ei,
                                               const float* __restrict__ dis,
                                               const int* __restrict__ row0,
                                               int2* __restrict__ edge8)
{
    __shared__ int cl[SLN];
    const int b = blockIdx.x >> 4, s = blockIdx.x & 15;
    const int lo = b * NN + s * SLN;            // global node range
    for (int i = threadIdx.x; i < SLN; i += 256) cl[i] = 0;
    __syncthreads();
    const int base = b * EPB;
    for (int i = threadIdx.x; i < EPB; i += 256) {
        int e = base + i;
        int d = ei[ETOT + e];
        if (d >= lo && d < lo + SLN) {
            int sr = ei[e];
            float nv = -(dis[sr] * dis[d]);
            int p = atomicAdd(&cl[d - lo], 1);
            edge8[row0[d] + p] = make_int2(sr, __float_as_int(nv));
        }
    }
}

// Encoder A matrix: [208][64] rows 0..191 = w_hh_enc, 192 = fc_w, rest 0. bf16 hi/lo.
__global__ void k_prepE(const float* __restrict__ whe, const float* __restrict__ fcw,
                        u16* __restrict__ AH, u16* __restrict__ AL)
{
    int i = blockIdx.x * blockDim.x + threadIdx.x;
    if (i < 208 * 64) {
        int r = i >> 6, k = i & 63;
        float v = (r < 192) ? whe[r * 64 + k] : ((r == 192) ? fcw[k] : 0.f);
        u16 hi = bfh(v);
        AH[i] = hi;
        AL[i] = bfh(v - bff(hi));
    }
}

// Decoder A matrix: [256][96].
__global__ void k_prepD(const float* __restrict__ whd, const float* __restrict__ wihd,
                        u16* __restrict__ AH, u16* __restrict__ AL)
{
    int i = blockIdx.x * blockDim.x + threadIdx.x;
    if (i < 256 * 96) {
        int r = i / 96, k = i - r * 96;
        float v = 0.f;
        if (k < 64) {
            if (r < 192) v = whd[r * 64 + k];
        } else if (k < 74) {
            int xi = k - 64;
            if (r < 128)       v = wihd[r * 10 + xi];
            else if (r >= 192) v = wihd[(r - 64) * 10 + xi];
        }
        u16 hi = bfh(v);
        AH[i] = hi;
        AL[i] = bfh(v - bff(hi));
    }
}

// ---------------- fused MFMA encoder (r11-proven) ----------------
__global__ __launch_bounds__(256, 2) void k_encM(
    const float* __restrict__ pm, const u16* __restrict__ AeH, const u16* __restrict__ AeL,
    const float* __restrict__ w_ih, const float* __restrict__ b_ih, const float* __restrict__ b_hh,
    const float* __restrict__ fc_b, const float* __restrict__ feat, const float* __restrict__ cw1,
    u16* __restrict__ BgH, u16* __restrict__ BgL, u16* __restrict__ Hb,
    float* __restrict__ xn_buf, float* __restrict__ y1)
{
    __shared__ u16 BH[2][EBLK * 64], BL[2][EBLK * 64];
    __shared__ float pmL[TH * EBLK];
    __shared__ float xnL[EBLK];

    const int tid = threadIdx.x;
    const int l   = tid & 63;
    const int wv  = __builtin_amdgcn_readfirstlane(tid >> 6);
    const int n0  = blockIdx.x * EBLK;
    const int cn  = l & 15;
    const int kg  = l >> 4;
    const int c0  = wv * 16 + kg * 4;

    for (int i = tid; i < EBLK * 64 / 2; i += 256) {
        ((uint32_t*)BH[0])[i] = 0u;
        ((uint32_t*)BL[0])[i] = 0u;
    }
    for (int i = tid; i < TH * EBLK; i += 256) {
        int t = i >> 5, n = i & 31;
        int node = n0 + n, b = node / NN, nn2 = node - b * NN;
        pmL[i] = pm[(b * TH + t) * NN + nn2];
    }
    bf16x8 AHf[4][2], ALf[4][2];
    #pragma unroll
    for (int s = 0; s < 4; s++) {
        #pragma unroll
        for (int ks = 0; ks < 2; ks++) {
            bf16x8 zh = {0,0,0,0,0,0,0,0};
            AHf[s][ks] = zh; ALf[s][ks] = zh;
            if (s < 3 || wv == 0) {
                int row = (wv + 4 * s) * 16 + cn;
                int off = row * 64 + ks * 32 + kg * 8;
                AHf[s][ks] = *(const bf16x8*)(AeH + off);
                ALf[s][ks] = *(const bf16x8*)(AeL + off);
            }
        }
    }
    float bR[4], bZ[4], biN[4], bhN[4];
    float wR0[4], wR1[4], wZ0[4], wZ1[4], wN0[4], wN1[4];
    #pragma unroll
    for (int j = 0; j < 4; j++) {
        int c = c0 + j;
        bR[j]  = b_ih[c] + b_hh[c];
        bZ[j]  = b_ih[64 + c] + b_hh[64 + c];
        biN[j] = b_ih[128 + c];
        bhN[j] = b_hh[128 + c];
        wR0[j] = w_ih[2 * c];           wR1[j] = w_ih[2 * c + 1];
        wZ0[j] = w_ih[2 * (64 + c)];    wZ1[j] = w_ih[2 * (64 + c) + 1];
        wN0[j] = w_ih[2 * (128 + c)];   wN1[j] = w_ih[2 * (128 + c) + 1];
    }
    const float fcb = fc_b[0];
    int baddr[2][2], haddr[2];
    #pragma unroll
    for (int ct = 0; ct < 2; ct++) {
        const int n = ct * 16 + cn;
        #pragma unroll
        for (int ks = 0; ks < 2; ks++)
            baddr[ct][ks] = (n * 64 + ks * 32 + kg * 8) ^ ((n & 7) << 3);
        haddr[ct] = (n * 64 + c0) ^ ((n & 7) << 3);
    }
    const int xn_  = tid >> 3, xsl = tid & 7;
    const int xidx = (xn_ * 64 + xsl * 8) ^ ((xn_ & 7) << 3);
    u16* const xdst = Hb + (size_t)(n0 + xn_) * (TH * HID) + xsl * 8;
    float hreg[2][4] = {{0.f,0.f,0.f,0.f},{0.f,0.f,0.f,0.f}};
    __syncthreads();

    for (int t = 0; t < TH; t++) {
        const int cur = t & 1, nxt = cur ^ 1;
        f32x4 acc[4][2];
        #pragma unroll
        for (int s = 0; s < 4; s++)
            #pragma unroll
            for (int ct = 0; ct < 2; ct++)
                acc[s][ct] = (f32x4){0.f, 0.f, 0.f, 0.f};

        #pragma unroll
        for (int ct = 0; ct < 2; ct++) {
            #pragma unroll
            for (int ks = 0; ks < 2; ks++) {
                bf16x8 bh = *(const bf16x8*)&BH[cur][baddr[ct][ks]];
                bf16x8 bl = *(const bf16x8*)&BL[cur][baddr[ct][ks]];
                #pragma unroll
                for (int s = 0; s < 4; s++) {
                    if (s < 3 || wv == 0) {
                        acc[s][ct] = __builtin_amdgcn_mfma_f32_16x16x32_bf16(AHf[s][ks], bh, acc[s][ct], 0, 0, 0);
                        acc[s][ct] = __builtin_amdgcn_mfma_f32_16x16x32_bf16(AHf[s][ks], bl, acc[s][ct], 0, 0, 0);
                        acc[s][ct] = __builtin_amdgcn_mfma_f32_16x16x32_bf16(ALf[s][ks], bh, acc[s][ct], 0, 0, 0);
                    }
                }
            }
        }
        if (wv == 0 && kg == 0) {
            #pragma unroll
            for (int ct = 0; ct < 2; ct++) xnL[ct * 16 + cn] = acc[3][ct][0];
        }
        __syncthreads();   // xnL ready

        #pragma unroll
        for (int ct = 0; ct < 2; ct++) {
            float xn = 0.f;
            if (t > 0) xn = xnL[ct * 16 + cn] + fcb;
            const float pv = pmL[t * EBLK + ct * 16 + cn];
            float hnew[4];
            #pragma unroll
            for (int j = 0; j < 4; j++) {
                float r  = sigmoidf_(acc[0][ct][j] + bR[j] + wR0[j] * xn + wR1[j] * pv);
                float z  = sigmoidf_(acc[1][ct][j] + bZ[j] + wZ0[j] * xn + wZ1[j] * pv);
                float gi = biN[j] + wN0[j] * xn + wN1[j] * pv;
                float gh = acc[2][ct][j] + bhN[j];
                float nn_ = tanhf_(gi + r * gh);
                hnew[j] = (1.f - z) * nn_ + z * hreg[ct][j];
                hreg[ct][j] = hnew[j];
            }
            u16 nh0 = bfh(hnew[0]), nh1 = bfh(hnew[1]), nh2 = bfh(hnew[2]), nh3 = bfh(hnew[3]);
            u16 nl0 = bfh(hnew[0] - bff(nh0)), nl1 = bfh(hnew[1] - bff(nh1));
            u16 nl2 = bfh(hnew[2] - bff(nh2)), nl3 = bfh(hnew[3] - bff(nh3));
            *(uint2*)&BH[nxt][haddr[ct]] = make_uint2(pk(nh0, nh1), pk(nh2, nh3));
            *(uint2*)&BL[nxt][haddr[ct]] = make_uint2(pk(nl0, nl1), pk(nl2, nl3));
        }
        __syncthreads();   // B[nxt] complete

        *(uint4*)(xdst + t * HID) = *(const uint4*)&BH[nxt][xidx];
    }

    if (wv == 0) {
        f32x4 ax[2];
        #pragma unroll
        for (int ct = 0; ct < 2; ct++) ax[ct] = (f32x4){0.f, 0.f, 0.f, 0.f};
        #pragma unroll
        for (int ct = 0; ct < 2; ct++) {
            #pragma unroll
            for (int ks = 0; ks < 2; ks++) {
                bf16x8 bh = *(const bf16x8*)&BH[0][baddr[ct][ks]];
                bf16x8 bl = *(const bf16x8*)&BL[0][baddr[ct][ks]];
                ax[ct] = __builtin_amdgcn_mfma_f32_16x16x32_bf16(AHf[3][ks], bh, ax[ct], 0, 0, 0);
                ax[ct] = __builtin_amdgcn_mfma_f32_16x16x32_bf16(AHf[3][ks], bl, ax[ct], 0, 0, 0);
                ax[ct] = __builtin_amdgcn_mfma_f32_16x16x32_bf16(ALf[3][ks], bh, ax[ct], 0, 0, 0);
            }
        }
        if (kg == 0) {
            #pragma unroll
            for (int ct = 0; ct < 2; ct++) xnL[ct * 16 + cn] = ax[ct][0];
        }
    }
    __syncthreads();

    {
        *(uint4*)(BgH + ((size_t)(n0 + xn_)) * 64 + xsl * 8) = *(const uint4*)&BH[0][xidx];
        *(uint4*)(BgL + ((size_t)(n0 + xn_)) * 64 + xsl * 8) = *(const uint4*)&BL[0][xidx];
    }
    if (tid < EBLK) {
        int n = tid, node = n0 + n;
        float xv = xnL[n] + fcb;
        xn_buf[node] = xv;
        int b = node / NN, nn2 = node - b * NN;
        const float* fp = feat + ((size_t)(b * TT + TH) * NN + nn2) * NF;
        float yy = xv * cw1[0];
        #pragma unroll
        for (int q = 0; q < NF; q++) yy += fp[q] * cw1[1 + q];
        y1[node] = yy;
    }
}

// ---------------- fully fused decoder step (r12-proven) ----------------
__global__ __launch_bounds__(256, 2) void k_decA(
    const float* __restrict__ feat, const u16* __restrict__ AdH, const u16* __restrict__ AdL,
    const float* __restrict__ b_ih, const float* __restrict__ b_hh,
    const float* __restrict__ w0, const float* __restrict__ cb,
    float* __restrict__ xn_buf, const float* __restrict__ y1_in, float* __restrict__ y1_out,
    const int* __restrict__ row0, const int2* __restrict__ edge8,
    u16* __restrict__ BgH, u16* __restrict__ BgL,
    const u16* __restrict__ Hb, const float* __restrict__ out_w, const float* __restrict__ out_b,
    const float* __restrict__ cw1, float* __restrict__ out, int t)
{
    __shared__ u16 XH[64 * 96], XL[64 * 96];
    __shared__ float gpart[4][DBLK];
    __shared__ float hx[DBLK][68];

    const int tid = threadIdx.x;
    const int l   = tid & 63;
    const int wv  = __builtin_amdgcn_readfirstlane(tid >> 6);
    const int n0  = blockIdx.x * DBLK;
    const int cn  = l & 15, kg = l >> 4;
    const int c0  = wv * 16 + kg * 4;

    // phase A: edge gather (4 lanes/node)
    {
        const int na = tid >> 2;
        const int q  = tid & 3;
        const int nd = n0 + na;
        const int beg = row0[nd], end = row0[nd + 1];
        float acc = 0.f;
        for (int i = beg + q; i < end; i += 4) {
            const int2 e = edge8[i];
            acc = fmaf(__int_as_float(e.y), y1_in[e.x], acc);
        }
        gpart[q][na] = acc;
    }
    // phase A2: stage h rows into LDS
    for (int i = tid; i < 512; i += 256) {
        int n = i >> 3, sl = i & 7;
        int idx = (n * 96 + sl * 8) ^ ((n & 7) << 3);
        *(uint4*)&XH[idx] = *(const uint4*)(BgH + ((size_t)(n0 + n)) * 64 + sl * 8);
        *(uint4*)&XL[idx] = *(const uint4*)(BgL + ((size_t)(n0 + n)) * 64 + sl * 8);
    }
    // A fragments + biases
    bf16x8 AHf[4][3], ALf[4][3];
    #pragma unroll
    for (int s = 0; s < 4; s++) {
        #pragma unroll
        for (int ks = 0; ks < 3; ks++) {
            bf16x8 zh = {0,0,0,0,0,0,0,0};
            AHf[s][ks] = zh; ALf[s][ks] = zh;
            const bool live = (s < 2) || (s == 2 && ks < 2) || (s == 3 && ks == 2);
            if (live) {
                int row = (wv + 4 * s) * 16 + cn;
                int off = row * 96 + ks * 32 + kg * 8;
                AHf[s][ks] = *(const bf16x8*)(AdH + off);
                ALf[s][ks] = *(const bf16x8*)(AdL + off);
            }
        }
    }
    float bsR[4], bsZ[4], biN[4], bhN[4];
    #pragma unroll
    for (int j = 0; j < 4; j++) {
        int c = c0 + j;
        bsR[j] = b_ih[c] + b_hh[c];
        bsZ[j] = b_ih[64 + c] + b_hh[64 + c];
        biN[j] = b_ih[128 + c];
        bhN[j] = b_hh[128 + c];
    }
    __syncthreads();   // gpart + h rows ready

    // phase B: x-row staging (tid<64)
    if (tid < DBLK) {
        int n = tid, node = n0 + n;
        int b = node / NN, nn2 = node - b * NN;
        float txv = gpart[0][n] + gpart[1][n] + gpart[2][n] + gpart[3][n];
        float x0 = xn_buf[node];
        const float* fp = feat + ((size_t)(b * TT + TH + t) * NN + nn2) * NF;
        float f0 = fp[0], f1 = fp[1], f2 = fp[2], f3 = fp[3];
        float f4 = fp[4], f5 = fp[5], f6 = fp[6], f7 = fp[7];
        float xw = x0 * w0[0];
        xw = fmaf(f0, w0[1], xw); xw = fmaf(f1, w0[2], xw);
        xw = fmaf(f2, w0[3], xw); xw = fmaf(f3, w0[4], xw);
        xw = fmaf(f4, w0[5], xw); xw = fmaf(f5, w0[6], xw);
        xw = fmaf(f6, w0[7], xw); xw = fmaf(f7, w0[8], xw);
        float xg = sigmoidf_(xw + txv + cb[0]);
        u16 h0 = bfh(x0), h1 = bfh(f0), h2 = bfh(f1), h3 = bfh(f2), h4 = bfh(f3);
        u16 h5 = bfh(f4), h6 = bfh(f5), h7 = bfh(f6), h8 = bfh(f7), h9 = bfh(xg);
        u16 l0 = bfh(x0 - bff(h0)), l1 = bfh(f0 - bff(h1)), l2 = bfh(f1 - bff(h2));
        u16 l3 = bfh(f2 - bff(h3)), l4 = bfh(f3 - bff(h4)), l5 = bfh(f4 - bff(h5));
        u16 l6 = bfh(f5 - bff(h6)), l7 = bfh(f6 - bff(h7)), l8 = bfh(f7 - bff(h8));
        u16 l9 = bfh(xg - bff(h9));
        uint4 qh0 = make_uint4(pk(h0, h1), pk(h2, h3), pk(h4, h5), pk(h6, h7));
        uint4 qh1 = make_uint4(pk(h8, h9), 0u, 0u, 0u);
        uint4 ql0 = make_uint4(pk(l0, l1), pk(l2, l3), pk(l4, l5), pk(l6, l7));
        uint4 ql1 = make_uint4(pk(l8, l9), 0u, 0u, 0u);
        uint4 zz  = make_uint4(0u, 0u, 0u, 0u);
        const int sw = (n & 7) << 3;
        *(uint4*)&XH[(n * 96 + 64) ^ sw] = qh0;
        *(uint4*)&XH[(n * 96 + 72) ^ sw] = qh1;
        *(uint4*)&XH[(n * 96 + 80) ^ sw] = zz;
        *(uint4*)&XH[(n * 96 + 88) ^ sw] = zz;
        *(uint4*)&XL[(n * 96 + 64) ^ sw] = ql0;
        *(uint4*)&XL[(n * 96 + 72) ^ sw] = ql1;
        *(uint4*)&XL[(n * 96 + 80) ^ sw] = zz;
        *(uint4*)&XL[(n * 96 + 88) ^ sw] = zz;
    }
    __syncthreads();   // X complete

    // phase C: MFMA
    f32x4 acc[4][4];
    #pragma unroll
    for (int s = 0; s < 4; s++)
        #pragma unroll
        for (int ct = 0; ct < 4; ct++)
            acc[s][ct] = (f32x4){0.f, 0.f, 0.f, 0.f};

    #pragma unroll
    for (int ct = 0; ct < 4; ct++) {
        const int n = ct * 16 + cn;
        #pragma unroll
        for (int ks = 0; ks < 3; ks++) {
            const int idx = (n * 96 + ks * 32 + kg * 8) ^ ((n & 7) << 3);
            bf16x8 bh = *(const bf16x8*)&XH[idx];
            bf16x8 bl = *(const bf16x8*)&XL[idx];
            #pragma unroll
            for (int s = 0; s < 4; s++) {
                const bool live = (s < 2) || (s == 2 && ks < 2) || (s == 3 && ks == 2);
                if (live) {
                    acc[s][ct] = __builtin_amdgcn_mfma_f32_16x16x32_bf16(AHf[s][ks], bh, acc[s][ct], 0, 0, 0);
                    acc[s][ct] = __builtin_amdgcn_mfma_f32_16x16x32_bf16(AHf[s][ks], bl, acc[s][ct], 0, 0, 0);
                    acc[s][ct] = __builtin_amdgcn_mfma_f32_16x16x32_bf16(ALf[s][ks], bh, acc[s][ct], 0, 0, 0);
                }
            }
        }
    }

    // phase D: epilogue -> h' to global (hi/lo) + LDS fp32 for attention
    #pragma unroll
    for (int ct = 0; ct < 4; ct++) {
        const int n = ct * 16 + cn, node = n0 + n;
        const int hidx = (n * 96 + c0) ^ ((n & 7) << 3);
        uint2 oh = *(const uint2*)&XH[hidx];
        uint2 ol = *(const uint2*)&XL[hidx];
        float hnew[4];
        #pragma unroll
        for (int j = 0; j < 4; j++) {
            u16 hh = (j < 2) ? (u16)((j == 0) ? (oh.x & 0xffff) : (oh.x >> 16))
                             : (u16)((j == 2) ? (oh.y & 0xffff) : (oh.y >> 16));
            u16 ll = (j < 2) ? (u16)((j == 0) ? (ol.x & 0xffff) : (ol.x >> 16))
                             : (u16)((j == 2) ? (ol.y & 0xffff) : (ol.y >> 16));
            float hold = bff(hh) + bff(ll);
            float r  = sigmoidf_(acc[0][ct][j] + bsR[j]);
            float z  = sigmoidf_(acc[1][ct][j] + bsZ[j]);
            float nn_ = tanhf_((acc[3][ct][j] + biN[j]) + r * (acc[2][ct][j] + bhN[j]));
            hnew[j] = (1.f - z) * nn_ + z * hold;
        }
        u16 nh0 = bfh(hnew[0]), nh1 = bfh(hnew[1]), nh2 = bfh(hnew[2]), nh3 = bfh(hnew[3]);
        u16 nl0 = bfh(hnew[0] - bff(nh0)), nl1 = bfh(hnew[1] - bff(nh1));
        u16 nl2 = bfh(hnew[2] - bff(nh2)), nl3 = bfh(hnew[3] - bff(nh3));
        *(uint2*)(BgH + (size_t)node * 64 + c0) = make_uint2(pk(nh0, nh1), pk(nh2, nh3));
        *(uint2*)(BgL + (size_t)node * 64 + c0) = make_uint2(pk(nl0, nl1), pk(nl2, nl3));
        *(float4*)&hx[n][c0] = make_float4(hnew[0], hnew[1], hnew[2], hnew[3]);
    }
    __syncthreads();   // hx ready

    // phase E: attention — 4 lanes per node, online softmax, single pass over Hb
    {
        const int g = tid >> 2;        // node slot in block
        const int q = tid & 3;         // channel quarter: d = q*16 .. q*16+15
        const int node = n0 + g;
        float hval[16];
        #pragma unroll
        for (int i = 0; i < 4; i++) {
            float4 v = *(const float4*)&hx[g][q * 16 + 4 * i];
            hval[4 * i]     = v.x; hval[4 * i + 1] = v.y;
            hval[4 * i + 2] = v.z; hval[4 * i + 3] = v.w;
        }
        const u16* Hrow = Hb + (size_t)node * (TH * HID) + q * 16;

        float m = -3.0e38f, s = 0.f;
        float aq[16];
        #pragma unroll
        for (int i = 0; i < 16; i++) aq[i] = 0.f;

        for (int tt = 0; tt < TH; tt++) {
            const uint4 v0 = *(const uint4*)(Hrow + tt * HID);
            const uint4 v1 = *(const uint4*)(Hrow + tt * HID + 8);
            float Hf[16];
            Hf[0]  = __uint_as_float(v0.x << 16); Hf[1]  = __uint_as_float(v0.x & 0xffff0000u);
            Hf[2]  = __uint_as_float(v0.y << 16); Hf[3]  = __uint_as_float(v0.y & 0xffff0000u);
            Hf[4]  = __uint_as_float(v0.z << 16); Hf[5]  = __uint_as_float(v0.z & 0xffff0000u);
            Hf[6]  = __uint_as_float(v0.w << 16); Hf[7]  = __uint_as_float(v0.w & 0xffff0000u);
            Hf[8]  = __uint_as_float(v1.x << 16); Hf[9]  = __uint_as_float(v1.x & 0xffff0000u);
            Hf[10] = __uint_as_float(v1.y << 16); Hf[11] = __uint_as_float(v1.y & 0xffff0000u);
            Hf[12] = __uint_as_float(v1.z << 16); Hf[13] = __uint_as_float(v1.z & 0xffff0000u);
            Hf[14] = __uint_as_float(v1.w << 16); Hf[15] = __uint_as_float(v1.w & 0xffff0000u);
            float p = 0.f;
            #pragma unroll
            for (int i = 0; i < 16; i++) p = fmaf(Hf[i], hval[i], p);
            p += __shfl_xor(p, 1, 64);
            p += __shfl_xor(p, 2, 64);   // p = full energy, uniform in 4-lane group
            const float mn = fmaxf(m, p);
            const float c  = __expf(m - mn);
            const float w  = __expf(p - mn);
            s = s * c + w;
            #pragma unroll
            for (int i = 0; i < 16; i++) aq[i] = fmaf(aq[i], c, w * Hf[i]);
            m = mn;
        }
        const float rs = 1.f / s;

        // out projection: concat(a, h) . out_w, reduced over the 4-lane group
        float part = 0.f;
        #pragma unroll
        for (int i = 0; i < 16; i++) {
            part = fmaf(out_w[q * 16 + i],       aq[i] * rs, part);
            part = fmaf(out_w[HID + q * 16 + i], hval[i],    part);
        }
        part += __shfl_xor(part, 1, 64);
        part += __shfl_xor(part, 2, 64);
        const float xnew = part + out_b[0];

        if (q == 0) {
            const int b = node / NN, n = node - b * NN;
            out[(b * TF + t) * NN + n] = xnew;
            xn_buf[node] = xnew;
            if (t + 1 < TF) {
                const float* fp = feat + ((size_t)(b * TT + TH + t + 1) * NN + n) * NF;
                float yy = xnew * cw1[0];
                #pragma unroll
                for (int c2 = 0; c2 < NF; c2++) yy += fp[c2] * cw1[1 + c2];
                y1_out[node] = yy;
            }
        }
    }
}

// ---------------- host launch ----------------
extern "C" void kernel_launch(void* const* d_in, const int* in_sizes, int n_in,
                              void* d_out, int out_size, void* d_ws, size_t ws_size,
                              hipStream_t stream)
{
    const float* pm     = (const float*)d_in[0];
    const float* feat   = (const float*)d_in[1];
    const int*   ei     = (const int*)d_in[2];
    const float* w_ih_e = (const float*)d_in[3];
    const float* w_hh_e = (const float*)d_in[4];
    const float* b_ih_e = (const float*)d_in[5];
    const float* b_hh_e = (const float*)d_in[6];
    const float* fc_w   = (const float*)d_in[7];
    const float* fc_b   = (const float*)d_in[8];
    const float* cw0    = (const float*)d_in[9];
    const float* cw1    = (const float*)d_in[10];
    const float* cb     = (const float*)d_in[11];
    const float* w_ih_d = (const float*)d_in[12];
    const float* w_hh_d = (const float*)d_in[13];
    const float* b_ih_d = (const float*)d_in[14];
    const float* b_hh_d = (const float*)d_in[15];
    const float* out_w  = (const float*)d_in[16];
    const float* out_b  = (const float*)d_in[17];
    float* out = (float*)d_out;

    char* ws = (char*)d_ws;
    size_t off = 0;
    auto alloc = [&](size_t bytes) -> void* {
        void* p = ws + off;
        off += (bytes + 255) & ~(size_t)255;
        return p;
    };
    u16* Hb    = (u16*)alloc(sizeof(u16) * (size_t)NODES * TH * HID);
    u16* BgH   = (u16*)alloc(sizeof(u16) * (size_t)NODES * HID);
    u16* BgL   = (u16*)alloc(sizeof(u16) * (size_t)NODES * HID);
    float* xn  = (float*)alloc(sizeof(float) * NODES);
    float* dis = (float*)alloc(sizeof(float) * NODES);
    float* y1A = (float*)alloc(sizeof(float) * NODES);
    float* y1B = (float*)alloc(sizeof(float) * NODES);
    u16* AeH   = (u16*)alloc(sizeof(u16) * 208 * 64);
    u16* AeL   = (u16*)alloc(sizeof(u16) * 208 * 64);
    u16* AdH   = (u16*)alloc(sizeof(u16) * 256 * 96);
    u16* AdL   = (u16*)alloc(sizeof(u16) * 256 * 96);
    int* row0  = (int*)alloc(sizeof(int) * (NODES + 1));
    int2* edge8 = (int2*)alloc(sizeof(int2) * ETOT);
    if (off > ws_size) return;

    // setup: sliced LDS histograms (256 blocks each), scan, norms, CSR, weight prep
    k_deg3<<<NB * NSL, 256, 0, stream>>>(ei, dis);
    k_scan<<<1, 256, 0, stream>>>(dis, row0);
    k_dis<<<(NODES + 255) / 256, 256, 0, stream>>>(dis);
    k_fill3<<<NB * NSL, 256, 0, stream>>>(ei, dis, row0, edge8);
    k_prepE<<<(208 * 64 + 255) / 256, 256, 0, stream>>>(w_hh_e, fc_w, AeH, AeL);
    k_prepD<<<(256 * 96 + 255) / 256, 256, 0, stream>>>(w_hh_d, w_ih_d, AdH, AdL);

    // fused MFMA encoder
    k_encM<<<NEBLK, 256, 0, stream>>>(pm, AeH, AeL, w_ih_e, b_ih_e, b_hh_e,
                                      fc_b, feat, cw1, BgH, BgL, Hb, xn, y1A);

    // decoder: one fully fused kernel per step (y1 ping-pong; h single-buffered)
    for (int t = 0; t < TF; t++) {
        const float* yin = (t & 1) ? y1B : y1A;
        float* yout      = (t & 1) ? y1A : y1B;
        k_decA<<<NDBLK, 256, 0, stream>>>(feat, AdH, AdL, b_ih_d, b_hh_d,
                                          cw0, cb, xn, yin, yout, row0, edge8,
                                          BgH, BgL, Hb, out_w, out_b, cw1, out, t);
    }
}

// Round 16
// 1011.735 us; speedup vs baseline: 1.1230x; 1.1230x over previous
//
#include <hip/hip_runtime.h>
#include <hip/hip_bf16.h>
#include <cstddef>
#include <cstdint>

// Problem constants
constexpr int NB    = 16;
constexpr int NN    = 2000;
constexpr int TH    = 24;
constexpr int TF    = 24;
constexpr int HID   = 64;
constexpr int NF    = 8;
constexpr int NODES = NB * NN;      // 32000
constexpr int ETOT  = NODES * 32;   // 1,024,000
constexpr int TT    = TH + TF;      // 48
constexpr int EBLK  = 32;           // nodes per encoder block
constexpr int NEBLK = NODES / EBLK; // 1000
constexpr int DBLK  = 64;           // nodes per decoder block
constexpr int NDBLK = NODES / DBLK; // 500

typedef __attribute__((ext_vector_type(8))) short bf16x8;
typedef __attribute__((ext_vector_type(4))) float f32x4;
typedef uint16_t u16;

__device__ __forceinline__ float sigmoidf_(float x) { return 1.f / (1.f + __expf(-x)); }
__device__ __forceinline__ float tanhf_(float x) {
    float e = __expf(2.f * x);
    return 1.f - 2.f / (e + 1.f);
}
__device__ __forceinline__ u16 bfh(float x) {
    __hip_bfloat16 b = __float2bfloat16(x);
    u16 u; __builtin_memcpy(&u, &b, 2); return u;
}
__device__ __forceinline__ float bff(u16 u) { return __uint_as_float(((uint32_t)u) << 16); }
__device__ __forceinline__ uint32_t pk(u16 a, u16 b) { return (uint32_t)a | ((uint32_t)b << 16); }

// ---------------- setup kernels (round-12 proven: global atomics) ----------------
__global__ void k_init(float* __restrict__ dis) {
    int i = blockIdx.x * blockDim.x + threadIdx.x;
    if (i < NODES) dis[i] = 0.f;
}

__global__ void k_deg(const int* __restrict__ ei, float* __restrict__ deg) {
    int e = blockIdx.x * blockDim.x + threadIdx.x;
    if (e < ETOT) atomicAdd(&deg[ei[ETOT + e]], 1.0f);
}

__global__ __launch_bounds__(256) void k_scan(const float* __restrict__ degf,
                                              int* __restrict__ row0,
                                              int* __restrict__ cnt)
{
    __shared__ int part[256];
    const int tid = threadIdx.x;
    const int per = NODES / 256;
    const int base = tid * per;
    int s = 0;
    for (int i = 0; i < per; i++) s += (int)degf[base + i];
    part[tid] = s;
    __syncthreads();
    for (int off = 1; off < 256; off <<= 1) {
        int v = (tid >= off) ? part[tid - off] : 0;
        __syncthreads();
        part[tid] += v;
        __syncthreads();
    }
    int run = (tid == 0) ? 0 : part[tid - 1];
    for (int i = 0; i < per; i++) {
        row0[base + i] = run;
        cnt[base + i]  = 0;
        run += (int)degf[base + i];
    }
    if (tid == 255) row0[NODES] = run;
}

__global__ void k_dis(float* __restrict__ dis) {
    int i = blockIdx.x * blockDim.x + threadIdx.x;
    if (i < NODES) {
        float d = dis[i];
        dis[i] = (d > 0.f) ? rsqrtf(fmaxf(d, 1.f)) : 0.f;
    }
}

__global__ void k_fill(const int* __restrict__ ei, const float* __restrict__ dis,
                       const int* __restrict__ row0, int* __restrict__ cnt,
                       int2* __restrict__ edge8)
{
    int e = blockIdx.x * blockDim.x + threadIdx.x;
    if (e < ETOT) {
        int s = ei[e];
        int d = ei[ETOT + e];
        float nv = -(dis[s] * dis[d]);
        int p = atomicAdd(&cnt[d], 1);
        edge8[row0[d] + p] = make_int2(s, __float_as_int(nv));
    }
}

// Encoder A matrix: [208][64] rows 0..191 = w_hh_enc, 192 = fc_w, rest 0. bf16 hi/lo.
__global__ void k_prepE(const float* __restrict__ whe, const float* __restrict__ fcw,
                        u16* __restrict__ AH, u16* __restrict__ AL)
{
    int i = blockIdx.x * blockDim.x + threadIdx.x;
    if (i < 208 * 64) {
        int r = i >> 6, k = i & 63;
        float v = (r < 192) ? whe[r * 64 + k] : ((r == 192) ? fcw[k] : 0.f);
        u16 hi = bfh(v);
        AH[i] = hi;
        AL[i] = bfh(v - bff(hi));
    }
}

// Decoder A matrix: [256][96].
__global__ void k_prepD(const float* __restrict__ whd, const float* __restrict__ wihd,
                        u16* __restrict__ AH, u16* __restrict__ AL)
{
    int i = blockIdx.x * blockDim.x + threadIdx.x;
    if (i < 256 * 96) {
        int r = i / 96, k = i - r * 96;
        float v = 0.f;
        if (k < 64) {
            if (r < 192) v = whd[r * 64 + k];
        } else if (k < 74) {
            int xi = k - 64;
            if (r < 128)       v = wihd[r * 10 + xi];
            else if (r >= 192) v = wihd[(r - 64) * 10 + xi];
        }
        u16 hi = bfh(v);
        AH[i] = hi;
        AL[i] = bfh(v - bff(hi));
    }
}

// ---------------- fused MFMA encoder (r11-proven) ----------------
__global__ __launch_bounds__(256, 2) void k_encM(
    const float* __restrict__ pm, const u16* __restrict__ AeH, const u16* __restrict__ AeL,
    const float* __restrict__ w_ih, const float* __restrict__ b_ih, const float* __restrict__ b_hh,
    const float* __restrict__ fc_b, const float* __restrict__ feat, const float* __restrict__ cw1,
    u16* __restrict__ BgH, u16* __restrict__ BgL, u16* __restrict__ Hb,
    float* __restrict__ xn_buf, float* __restrict__ y1)
{
    __shared__ u16 BH[2][EBLK * 64], BL[2][EBLK * 64];
    __shared__ float pmL[TH * EBLK];
    __shared__ float xnL[EBLK];

    const int tid = threadIdx.x;
    const int l   = tid & 63;
    const int wv  = __builtin_amdgcn_readfirstlane(tid >> 6);
    const int n0  = blockIdx.x * EBLK;
    const int cn  = l & 15;
    const int kg  = l >> 4;
    const int c0  = wv * 16 + kg * 4;

    for (int i = tid; i < EBLK * 64 / 2; i += 256) {
        ((uint32_t*)BH[0])[i] = 0u;
        ((uint32_t*)BL[0])[i] = 0u;
    }
    for (int i = tid; i < TH * EBLK; i += 256) {
        int t = i >> 5, n = i & 31;
        int node = n0 + n, b = node / NN, nn2 = node - b * NN;
        pmL[i] = pm[(b * TH + t) * NN + nn2];
    }
    bf16x8 AHf[4][2], ALf[4][2];
    #pragma unroll
    for (int s = 0; s < 4; s++) {
        #pragma unroll
        for (int ks = 0; ks < 2; ks++) {
            bf16x8 zh = {0,0,0,0,0,0,0,0};
            AHf[s][ks] = zh; ALf[s][ks] = zh;
            if (s < 3 || wv == 0) {
                int row = (wv + 4 * s) * 16 + cn;
                int off = row * 64 + ks * 32 + kg * 8;
                AHf[s][ks] = *(const bf16x8*)(AeH + off);
                ALf[s][ks] = *(const bf16x8*)(AeL + off);
            }
        }
    }
    float bR[4], bZ[4], biN[4], bhN[4];
    float wR0[4], wR1[4], wZ0[4], wZ1[4], wN0[4], wN1[4];
    #pragma unroll
    for (int j = 0; j < 4; j++) {
        int c = c0 + j;
        bR[j]  = b_ih[c] + b_hh[c];
        bZ[j]  = b_ih[64 + c] + b_hh[64 + c];
        biN[j] = b_ih[128 + c];
        bhN[j] = b_hh[128 + c];
        wR0[j] = w_ih[2 * c];           wR1[j] = w_ih[2 * c + 1];
        wZ0[j] = w_ih[2 * (64 + c)];    wZ1[j] = w_ih[2 * (64 + c) + 1];
        wN0[j] = w_ih[2 * (128 + c)];   wN1[j] = w_ih[2 * (128 + c) + 1];
    }
    const float fcb = fc_b[0];
    int baddr[2][2], haddr[2];
    #pragma unroll
    for (int ct = 0; ct < 2; ct++) {
        const int n = ct * 16 + cn;
        #pragma unroll
        for (int ks = 0; ks < 2; ks++)
            baddr[ct][ks] = (n * 64 + ks * 32 + kg * 8) ^ ((n & 7) << 3);
        haddr[ct] = (n * 64 + c0) ^ ((n & 7) << 3);
    }
    const int xn_  = tid >> 3, xsl = tid & 7;
    const int xidx = (xn_ * 64 + xsl * 8) ^ ((xn_ & 7) << 3);
    u16* const xdst = Hb + (size_t)(n0 + xn_) * (TH * HID) + xsl * 8;
    float hreg[2][4] = {{0.f,0.f,0.f,0.f},{0.f,0.f,0.f,0.f}};
    __syncthreads();

    for (int t = 0; t < TH; t++) {
        const int cur = t & 1, nxt = cur ^ 1;
        f32x4 acc[4][2];
        #pragma unroll
        for (int s = 0; s < 4; s++)
            #pragma unroll
            for (int ct = 0; ct < 2; ct++)
                acc[s][ct] = (f32x4){0.f, 0.f, 0.f, 0.f};

        #pragma unroll
        for (int ct = 0; ct < 2; ct++) {
            #pragma unroll
            for (int ks = 0; ks < 2; ks++) {
                bf16x8 bh = *(const bf16x8*)&BH[cur][baddr[ct][ks]];
                bf16x8 bl = *(const bf16x8*)&BL[cur][baddr[ct][ks]];
                #pragma unroll
                for (int s = 0; s < 4; s++) {
                    if (s < 3 || wv == 0) {
                        acc[s][ct] = __builtin_amdgcn_mfma_f32_16x16x32_bf16(AHf[s][ks], bh, acc[s][ct], 0, 0, 0);
                        acc[s][ct] = __builtin_amdgcn_mfma_f32_16x16x32_bf16(AHf[s][ks], bl, acc[s][ct], 0, 0, 0);
                        acc[s][ct] = __builtin_amdgcn_mfma_f32_16x16x32_bf16(ALf[s][ks], bh, acc[s][ct], 0, 0, 0);
                    }
                }
            }
        }
        if (wv == 0 && kg == 0) {
            #pragma unroll
            for (int ct = 0; ct < 2; ct++) xnL[ct * 16 + cn] = acc[3][ct][0];
        }
        __syncthreads();   // xnL ready

        #pragma unroll
        for (int ct = 0; ct < 2; ct++) {
            float xn = 0.f;
            if (t > 0) xn = xnL[ct * 16 + cn] + fcb;
            const float pv = pmL[t * EBLK + ct * 16 + cn];
            float hnew[4];
            #pragma unroll
            for (int j = 0; j < 4; j++) {
                float r  = sigmoidf_(acc[0][ct][j] + bR[j] + wR0[j] * xn + wR1[j] * pv);
                float z  = sigmoidf_(acc[1][ct][j] + bZ[j] + wZ0[j] * xn + wZ1[j] * pv);
                float gi = biN[j] + wN0[j] * xn + wN1[j] * pv;
                float gh = acc[2][ct][j] + bhN[j];
                float nn_ = tanhf_(gi + r * gh);
                hnew[j] = (1.f - z) * nn_ + z * hreg[ct][j];
                hreg[ct][j] = hnew[j];
            }
            u16 nh0 = bfh(hnew[0]), nh1 = bfh(hnew[1]), nh2 = bfh(hnew[2]), nh3 = bfh(hnew[3]);
            u16 nl0 = bfh(hnew[0] - bff(nh0)), nl1 = bfh(hnew[1] - bff(nh1));
            u16 nl2 = bfh(hnew[2] - bff(nh2)), nl3 = bfh(hnew[3] - bff(nh3));
            *(uint2*)&BH[nxt][haddr[ct]] = make_uint2(pk(nh0, nh1), pk(nh2, nh3));
            *(uint2*)&BL[nxt][haddr[ct]] = make_uint2(pk(nl0, nl1), pk(nl2, nl3));
        }
        __syncthreads();   // B[nxt] complete

        *(uint4*)(xdst + t * HID) = *(const uint4*)&BH[nxt][xidx];
    }

    if (wv == 0) {
        f32x4 ax[2];
        #pragma unroll
        for (int ct = 0; ct < 2; ct++) ax[ct] = (f32x4){0.f, 0.f, 0.f, 0.f};
        #pragma unroll
        for (int ct = 0; ct < 2; ct++) {
            #pragma unroll
            for (int ks = 0; ks < 2; ks++) {
                bf16x8 bh = *(const bf16x8*)&BH[0][baddr[ct][ks]];
                bf16x8 bl = *(const bf16x8*)&BL[0][baddr[ct][ks]];
                ax[ct] = __builtin_amdgcn_mfma_f32_16x16x32_bf16(AHf[3][ks], bh, ax[ct], 0, 0, 0);
                ax[ct] = __builtin_amdgcn_mfma_f32_16x16x32_bf16(AHf[3][ks], bl, ax[ct], 0, 0, 0);
                ax[ct] = __builtin_amdgcn_mfma_f32_16x16x32_bf16(ALf[3][ks], bh, ax[ct], 0, 0, 0);
            }
        }
        if (kg == 0) {
            #pragma unroll
            for (int ct = 0; ct < 2; ct++) xnL[ct * 16 + cn] = ax[ct][0];
        }
    }
    __syncthreads();

    {
        *(uint4*)(BgH + ((size_t)(n0 + xn_)) * 64 + xsl * 8) = *(const uint4*)&BH[0][xidx];
        *(uint4*)(BgL + ((size_t)(n0 + xn_)) * 64 + xsl * 8) = *(const uint4*)&BL[0][xidx];
    }
    if (tid < EBLK) {
        int n = tid, node = n0 + n;
        float xv = xnL[n] + fcb;
        xn_buf[node] = xv;
        int b = node / NN, nn2 = node - b * NN;
        const float* fp = feat + ((size_t)(b * TT + TH) * NN + nn2) * NF;
        float yy = xv * cw1[0];
        #pragma unroll
        for (int q = 0; q < NF; q++) yy += fp[q] * cw1[1 + q];
        y1[node] = yy;
    }
}

// ---------------- fully fused decoder step (r12-proven) ----------------
__global__ __launch_bounds__(256, 2) void k_decA(
    const float* __restrict__ feat, const u16* __restrict__ AdH, const u16* __restrict__ AdL,
    const float* __restrict__ b_ih, const float* __restrict__ b_hh,
    const float* __restrict__ w0, const float* __restrict__ cb,
    float* __restrict__ xn_buf, const float* __restrict__ y1_in, float* __restrict__ y1_out,
    const int* __restrict__ row0, const int2* __restrict__ edge8,
    u16* __restrict__ BgH, u16* __restrict__ BgL,
    const u16* __restrict__ Hb, const float* __restrict__ out_w, const float* __restrict__ out_b,
    const float* __restrict__ cw1, float* __restrict__ out, int t)
{
    __shared__ u16 XH[64 * 96], XL[64 * 96];
    __shared__ float gpart[4][DBLK];
    __shared__ float hx[DBLK][68];

    const int tid = threadIdx.x;
    const int l   = tid & 63;
    const int wv  = __builtin_amdgcn_readfirstlane(tid >> 6);
    const int n0  = blockIdx.x * DBLK;
    const int cn  = l & 15, kg = l >> 4;
    const int c0  = wv * 16 + kg * 4;

    // phase A: edge gather (4 lanes/node)
    {
        const int na = tid >> 2;
        const int q  = tid & 3;
        const int nd = n0 + na;
        const int beg = row0[nd], end = row0[nd + 1];
        float acc = 0.f;
        for (int i = beg + q; i < end; i += 4) {
            const int2 e = edge8[i];
            acc = fmaf(__int_as_float(e.y), y1_in[e.x], acc);
        }
        gpart[q][na] = acc;
    }
    // phase A2: stage h rows into LDS
    for (int i = tid; i < 512; i += 256) {
        int n = i >> 3, sl = i & 7;
        int idx = (n * 96 + sl * 8) ^ ((n & 7) << 3);
        *(uint4*)&XH[idx] = *(const uint4*)(BgH + ((size_t)(n0 + n)) * 64 + sl * 8);
        *(uint4*)&XL[idx] = *(const uint4*)(BgL + ((size_t)(n0 + n)) * 64 + sl * 8);
    }
    // A fragments + biases
    bf16x8 AHf[4][3], ALf[4][3];
    #pragma unroll
    for (int s = 0; s < 4; s++) {
        #pragma unroll
        for (int ks = 0; ks < 3; ks++) {
            bf16x8 zh = {0,0,0,0,0,0,0,0};
            AHf[s][ks] = zh; ALf[s][ks] = zh;
            const bool live = (s < 2) || (s == 2 && ks < 2) || (s == 3 && ks == 2);
            if (live) {
                int row = (wv + 4 * s) * 16 + cn;
                int off = row * 96 + ks * 32 + kg * 8;
                AHf[s][ks] = *(const bf16x8*)(AdH + off);
                ALf[s][ks] = *(const bf16x8*)(AdL + off);
            }
        }
    }
    float bsR[4], bsZ[4], biN[4], bhN[4];
    #pragma unroll
    for (int j = 0; j < 4; j++) {
        int c = c0 + j;
        bsR[j] = b_ih[c] + b_hh[c];
        bsZ[j] = b_ih[64 + c] + b_hh[64 + c];
        biN[j] = b_ih[128 + c];
        bhN[j] = b_hh[128 + c];
    }
    __syncthreads();   // gpart + h rows ready

    // phase B: x-row staging (tid<64)
    if (tid < DBLK) {
        int n = tid, node = n0 + n;
        int b = node / NN, nn2 = node - b * NN;
        float txv = gpart[0][n] + gpart[1][n] + gpart[2][n] + gpart[3][n];
        float x0 = xn_buf[node];
        const float* fp = feat + ((size_t)(b * TT + TH + t) * NN + nn2) * NF;
        float f0 = fp[0], f1 = fp[1], f2 = fp[2], f3 = fp[3];
        float f4 = fp[4], f5 = fp[5], f6 = fp[6], f7 = fp[7];
        float xw = x0 * w0[0];
        xw = fmaf(f0, w0[1], xw); xw = fmaf(f1, w0[2], xw);
        xw = fmaf(f2, w0[3], xw); xw = fmaf(f3, w0[4], xw);
        xw = fmaf(f4, w0[5], xw); xw = fmaf(f5, w0[6], xw);
        xw = fmaf(f6, w0[7], xw); xw = fmaf(f7, w0[8], xw);
        float xg = sigmoidf_(xw + txv + cb[0]);
        u16 h0 = bfh(x0), h1 = bfh(f0), h2 = bfh(f1), h3 = bfh(f2), h4 = bfh(f3);
        u16 h5 = bfh(f4), h6 = bfh(f5), h7 = bfh(f6), h8 = bfh(f7), h9 = bfh(xg);
        u16 l0 = bfh(x0 - bff(h0)), l1 = bfh(f0 - bff(h1)), l2 = bfh(f1 - bff(h2));
        u16 l3 = bfh(f2 - bff(h3)), l4 = bfh(f3 - bff(h4)), l5 = bfh(f4 - bff(h5));
        u16 l6 = bfh(f5 - bff(h6)), l7 = bfh(f6 - bff(h7)), l8 = bfh(f7 - bff(h8));
        u16 l9 = bfh(xg - bff(h9));
        uint4 qh0 = make_uint4(pk(h0, h1), pk(h2, h3), pk(h4, h5), pk(h6, h7));
        uint4 qh1 = make_uint4(pk(h8, h9), 0u, 0u, 0u);
        uint4 ql0 = make_uint4(pk(l0, l1), pk(l2, l3), pk(l4, l5), pk(l6, l7));
        uint4 ql1 = make_uint4(pk(l8, l9), 0u, 0u, 0u);
        uint4 zz  = make_uint4(0u, 0u, 0u, 0u);
        const int sw = (n & 7) << 3;
        *(uint4*)&XH[(n * 96 + 64) ^ sw] = qh0;
        *(uint4*)&XH[(n * 96 + 72) ^ sw] = qh1;
        *(uint4*)&XH[(n * 96 + 80) ^ sw] = zz;
        *(uint4*)&XH[(n * 96 + 88) ^ sw] = zz;
        *(uint4*)&XL[(n * 96 + 64) ^ sw] = ql0;
        *(uint4*)&XL[(n * 96 + 72) ^ sw] = ql1;
        *(uint4*)&XL[(n * 96 + 80) ^ sw] = zz;
        *(uint4*)&XL[(n * 96 + 88) ^ sw] = zz;
    }
    __syncthreads();   // X complete

    // phase C: MFMA
    f32x4 acc[4][4];
    #pragma unroll
    for (int s = 0; s < 4; s++)
        #pragma unroll
        for (int ct = 0; ct < 4; ct++)
            acc[s][ct] = (f32x4){0.f, 0.f, 0.f, 0.f};

    #pragma unroll
    for (int ct = 0; ct < 4; ct++) {
        const int n = ct * 16 + cn;
        #pragma unroll
        for (int ks = 0; ks < 3; ks++) {
            const int idx = (n * 96 + ks * 32 + kg * 8) ^ ((n & 7) << 3);
            bf16x8 bh = *(const bf16x8*)&XH[idx];
            bf16x8 bl = *(const bf16x8*)&XL[idx];
            #pragma unroll
            for (int s = 0; s < 4; s++) {
                const bool live = (s < 2) || (s == 2 && ks < 2) || (s == 3 && ks == 2);
                if (live) {
                    acc[s][ct] = __builtin_amdgcn_mfma_f32_16x16x32_bf16(AHf[s][ks], bh, acc[s][ct], 0, 0, 0);
                    acc[s][ct] = __builtin_amdgcn_mfma_f32_16x16x32_bf16(AHf[s][ks], bl, acc[s][ct], 0, 0, 0);
                    acc[s][ct] = __builtin_amdgcn_mfma_f32_16x16x32_bf16(ALf[s][ks], bh, acc[s][ct], 0, 0, 0);
                }
            }
        }
    }

    // phase D: epilogue -> h' to global (hi/lo) + LDS fp32 for attention
    #pragma unroll
    for (int ct = 0; ct < 4; ct++) {
        const int n = ct * 16 + cn, node = n0 + n;
        const int hidx = (n * 96 + c0) ^ ((n & 7) << 3);
        uint2 oh = *(const uint2*)&XH[hidx];
        uint2 ol = *(const uint2*)&XL[hidx];
        float hnew[4];
        #pragma unroll
        for (int j = 0; j < 4; j++) {
            u16 hh = (j < 2) ? (u16)((j == 0) ? (oh.x & 0xffff) : (oh.x >> 16))
                             : (u16)((j == 2) ? (oh.y & 0xffff) : (oh.y >> 16));
            u16 ll = (j < 2) ? (u16)((j == 0) ? (ol.x & 0xffff) : (ol.x >> 16))
                             : (u16)((j == 2) ? (ol.y & 0xffff) : (ol.y >> 16));
            float hold = bff(hh) + bff(ll);
            float r  = sigmoidf_(acc[0][ct][j] + bsR[j]);
            float z  = sigmoidf_(acc[1][ct][j] + bsZ[j]);
            float nn_ = tanhf_((acc[3][ct][j] + biN[j]) + r * (acc[2][ct][j] + bhN[j]));
            hnew[j] = (1.f - z) * nn_ + z * hold;
        }
        u16 nh0 = bfh(hnew[0]), nh1 = bfh(hnew[1]), nh2 = bfh(hnew[2]), nh3 = bfh(hnew[3]);
        u16 nl0 = bfh(hnew[0] - bff(nh0)), nl1 = bfh(hnew[1] - bff(nh1));
        u16 nl2 = bfh(hnew[2] - bff(nh2)), nl3 = bfh(hnew[3] - bff(nh3));
        *(uint2*)(BgH + (size_t)node * 64 + c0) = make_uint2(pk(nh0, nh1), pk(nh2, nh3));
        *(uint2*)(BgL + (size_t)node * 64 + c0) = make_uint2(pk(nl0, nl1), pk(nl2, nl3));
        *(float4*)&hx[n][c0] = make_float4(hnew[0], hnew[1], hnew[2], hnew[3]);
    }
    __syncthreads();   // hx ready

    // phase E: attention — 4 lanes per node, online softmax, single pass over Hb
    {
        const int g = tid >> 2;        // node slot in block
        const int q = tid & 3;         // channel quarter: d = q*16 .. q*16+15
        const int node = n0 + g;
        float hval[16];
        #pragma unroll
        for (int i = 0; i < 4; i++) {
            float4 v = *(const float4*)&hx[g][q * 16 + 4 * i];
            hval[4 * i]     = v.x; hval[4 * i + 1] = v.y;
            hval[4 * i + 2] = v.z; hval[4 * i + 3] = v.w;
        }
        const u16* Hrow = Hb + (size_t)node * (TH * HID) + q * 16;

        float m = -3.0e38f, s = 0.f;
        float aq[16];
        #pragma unroll
        for (int i = 0; i < 16; i++) aq[i] = 0.f;

        for (int tt = 0; tt < TH; tt++) {
            const uint4 v0 = *(const uint4*)(Hrow + tt * HID);
            const uint4 v1 = *(const uint4*)(Hrow + tt * HID + 8);
            float Hf[16];
            Hf[0]  = __uint_as_float(v0.x << 16); Hf[1]  = __uint_as_float(v0.x & 0xffff0000u);
            Hf[2]  = __uint_as_float(v0.y << 16); Hf[3]  = __uint_as_float(v0.y & 0xffff0000u);
            Hf[4]  = __uint_as_float(v0.z << 16); Hf[5]  = __uint_as_float(v0.z & 0xffff0000u);
            Hf[6]  = __uint_as_float(v0.w << 16); Hf[7]  = __uint_as_float(v0.w & 0xffff0000u);
            Hf[8]  = __uint_as_float(v1.x << 16); Hf[9]  = __uint_as_float(v1.x & 0xffff0000u);
            Hf[10] = __uint_as_float(v1.y << 16); Hf[11] = __uint_as_float(v1.y & 0xffff0000u);
            Hf[12] = __uint_as_float(v1.z << 16); Hf[13] = __uint_as_float(v1.z & 0xffff0000u);
            Hf[14] = __uint_as_float(v1.w << 16); Hf[15] = __uint_as_float(v1.w & 0xffff0000u);
            float p = 0.f;
            #pragma unroll
            for (int i = 0; i < 16; i++) p = fmaf(Hf[i], hval[i], p);
            p += __shfl_xor(p, 1, 64);
            p += __shfl_xor(p, 2, 64);   // p = full energy, uniform in 4-lane group
            const float mn = fmaxf(m, p);
            const float c  = __expf(m - mn);
            const float w  = __expf(p - mn);
            s = s * c + w;
            #pragma unroll
            for (int i = 0; i < 16; i++) aq[i] = fmaf(aq[i], c, w * Hf[i]);
            m = mn;
        }
        const float rs = 1.f / s;

        // out projection: concat(a, h) . out_w, reduced over the 4-lane group
        float part = 0.f;
        #pragma unroll
        for (int i = 0; i < 16; i++) {
            part = fmaf(out_w[q * 16 + i],       aq[i] * rs, part);
            part = fmaf(out_w[HID + q * 16 + i], hval[i],    part);
        }
        part += __shfl_xor(part, 1, 64);
        part += __shfl_xor(part, 2, 64);
        const float xnew = part + out_b[0];

        if (q == 0) {
            const int b = node / NN, n = node - b * NN;
            out[(b * TF + t) * NN + n] = xnew;
            xn_buf[node] = xnew;
            if (t + 1 < TF) {
                const float* fp = feat + ((size_t)(b * TT + TH + t + 1) * NN + n) * NF;
                float yy = xnew * cw1[0];
                #pragma unroll
                for (int c2 = 0; c2 < NF; c2++) yy += fp[c2] * cw1[1 + c2];
                y1_out[node] = yy;
            }
        }
    }
}

// ---------------- host launch ----------------
extern "C" void kernel_launch(void* const* d_in, const int* in_sizes, int n_in,
                              void* d_out, int out_size, void* d_ws, size_t ws_size,
                              hipStream_t stream)
{
    const float* pm     = (const float*)d_in[0];
    const float* feat   = (const float*)d_in[1];
    const int*   ei     = (const int*)d_in[2];
    const float* w_ih_e = (const float*)d_in[3];
    const float* w_hh_e = (const float*)d_in[4];
    const float* b_ih_e = (const float*)d_in[5];
    const float* b_hh_e = (const float*)d_in[6];
    const float* fc_w   = (const float*)d_in[7];
    const float* fc_b   = (const float*)d_in[8];
    const float* cw0    = (const float*)d_in[9];
    const float* cw1    = (const float*)d_in[10];
    const float* cb     = (const float*)d_in[11];
    const float* w_ih_d = (const float*)d_in[12];
    const float* w_hh_d = (const float*)d_in[13];
    const float* b_ih_d = (const float*)d_in[14];
    const float* b_hh_d = (const float*)d_in[15];
    const float* out_w  = (const float*)d_in[16];
    const float* out_b  = (const float*)d_in[17];
    float* out = (float*)d_out;

    char* ws = (char*)d_ws;
    size_t off = 0;
    auto alloc = [&](size_t bytes) -> void* {
        void* p = ws + off;
        off += (bytes + 255) & ~(size_t)255;
        return p;
    };
    u16* Hb    = (u16*)alloc(sizeof(u16) * (size_t)NODES * TH * HID);
    u16* BgH   = (u16*)alloc(sizeof(u16) * (size_t)NODES * HID);
    u16* BgL   = (u16*)alloc(sizeof(u16) * (size_t)NODES * HID);
    float* xn  = (float*)alloc(sizeof(float) * NODES);
    float* dis = (float*)alloc(sizeof(float) * NODES);
    float* y1A = (float*)alloc(sizeof(float) * NODES);
    float* y1B = (float*)alloc(sizeof(float) * NODES);
    u16* AeH   = (u16*)alloc(sizeof(u16) * 208 * 64);
    u16* AeL   = (u16*)alloc(sizeof(u16) * 208 * 64);
    u16* AdH   = (u16*)alloc(sizeof(u16) * 256 * 96);
    u16* AdL   = (u16*)alloc(sizeof(u16) * 256 * 96);
    int* row0  = (int*)alloc(sizeof(int) * (NODES + 1));
    int* cnt   = (int*)alloc(sizeof(int) * NODES);
    int2* edge8 = (int2*)alloc(sizeof(int2) * ETOT);
    if (off > ws_size) return;

    // setup (round-12 proven): global-atomic degree + CSR fill
    k_init<<<(NODES + 255) / 256, 256, 0, stream>>>(dis);
    k_deg<<<(ETOT + 255) / 256, 256, 0, stream>>>(ei, dis);
    k_scan<<<1, 256, 0, stream>>>(dis, row0, cnt);
    k_dis<<<(NODES + 255) / 256, 256, 0, stream>>>(dis);
    k_fill<<<(ETOT + 255) / 256, 256, 0, stream>>>(ei, dis, row0, cnt, edge8);
    k_prepE<<<(208 * 64 + 255) / 256, 256, 0, stream>>>(w_hh_e, fc_w, AeH, AeL);
    k_prepD<<<(256 * 96 + 255) / 256, 256, 0, stream>>>(w_hh_d, w_ih_d, AdH, AdL);

    // fused MFMA encoder
    k_encM<<<NEBLK, 256, 0, stream>>>(pm, AeH, AeL, w_ih_e, b_ih_e, b_hh_e,
                                      fc_b, feat, cw1, BgH, BgL, Hb, xn, y1A);

    // decoder: one fully fused kernel per step (y1 ping-pong; h single-buffered)
    for (int t = 0; t < TF; t++) {
        const float* yin = (t & 1) ? y1B : y1A;
        float* yout      = (t & 1) ? y1A : y1B;
        k_decA<<<NDBLK, 256, 0, stream>>>(feat, AdH, AdL, b_ih_d, b_hh_d,
                                          cw0, cb, xn, yin, yout, row0, edge8,
                                          BgH, BgL, Hb, out_w, out_b, cw1, out, t);
    }
}